// Round 1
// baseline (848.187 us; speedup 1.0000x reference)
//
#include <hip/hip_runtime.h>
#include <math.h>

typedef unsigned short ushort_t;
typedef unsigned int uint_t;
typedef __attribute__((ext_vector_type(8))) short short8;
typedef __attribute__((ext_vector_type(4))) float floatx4;

// Problem dims
constexpr int B = 8;
constexpr int S = 2048;
constexpr int D = 512;
constexpr int BS = B * S;          // 16384 rows
constexpr float LN_EPS = 1e-5f;
constexpr float ATTN_SCALE = 0.04419417382415922f;  // 1/sqrt(512)

// R5 lesson (post-timing absmax 4.0, dur unchanged): global_load_lds staging
// on this toolchain gave 0 speedup and corrupted post-warm replays -> reverted
// to R4's proven padded-LDS VGPR staging. Also: do NOT alias Fb onto CDb/NXb —
// the gate epilogue of a fast n-block clobbers A-tiles still being staged by
// sibling n-blocks of the same m-range (cross-block race).
// R6: qk/pv/ffn moved from 128x64/BK=32 core (8 MFMA per barrier-pair/wave,
// 275 TF) to 128x128/BK=64 core (32 MFMA per barrier-pair/wave). X converted
// to bf16 row-major (Xb, fused into the X transpose) so qk is pure-bf16.
// Xb lives in slot0 and is consumed group-by-group exactly as attnb (pv
// output) overwrites it: pv g0 writes batches 0-3 only after qk g0 read them;
// qk g1 reads batches 4-7 which pv hasn't touched yet. Stream-ordered => safe.

// ---------------------------------------------------------------------------
// bf16 helpers (RNE)
// ---------------------------------------------------------------------------
__device__ __forceinline__ ushort_t f2bf(float f) {
    union { float f; uint_t u; } x; x.f = f;
    uint_t r = x.u + 0x7fffu + ((x.u >> 16) & 1u);
    return (ushort_t)(r >> 16);
}
__device__ __forceinline__ float bf2f(ushort_t h) {
    union { uint_t u; float f; } y; y.u = ((uint_t)h) << 16;
    return y.f;
}
__device__ __forceinline__ short8 pack8(float4 a, float4 b) {
    short8 p;
    p[0] = (short)f2bf(a.x); p[1] = (short)f2bf(a.y);
    p[2] = (short)f2bf(a.z); p[3] = (short)f2bf(a.w);
    p[4] = (short)f2bf(b.x); p[5] = (short)f2bf(b.y);
    p[6] = (short)f2bf(b.z); p[7] = (short)f2bf(b.w);
    return p;
}

// ---------------------------------------------------------------------------
// Reductions (256-thread blocks = 4 waves of 64)
// ---------------------------------------------------------------------------
__device__ __forceinline__ float blk_reduce_sum(float v, float* sm) {
#pragma unroll
    for (int o = 32; o; o >>= 1) v += __shfl_down(v, o, 64);
    __syncthreads();
    if ((threadIdx.x & 63) == 0) sm[threadIdx.x >> 6] = v;
    __syncthreads();
    return sm[0] + sm[1] + sm[2] + sm[3];
}
__device__ __forceinline__ float blk_reduce_max(float v, float* sm) {
#pragma unroll
    for (int o = 32; o; o >>= 1) v = fmaxf(v, __shfl_down(v, o, 64));
    __syncthreads();
    if ((threadIdx.x & 63) == 0) sm[threadIdx.x >> 6] = v;
    __syncthreads();
    return fmaxf(fmaxf(sm[0], sm[1]), fmaxf(sm[2], sm[3]));
}

// ---------------------------------------------------------------------------
// fp32 [R][C] -> bf16 [C][R] transpose+convert; batched via blockIdx.z (z*R*C)
// Optionally also emits the straight (non-transposed) bf16 copy into out2.
// ---------------------------------------------------------------------------
__global__ __launch_bounds__(256) void transpose_cvt(
    const float* __restrict__ in, ushort_t* __restrict__ out, int R, int C,
    ushort_t* __restrict__ out2) {
    __shared__ float tl[32][33];
    const size_t zoff = (size_t)blockIdx.z * R * C;
    const int tx = threadIdx.x & 31, ty = threadIdx.x >> 5;  // ty 0..7
    const int c0 = blockIdx.x * 32, r0 = blockIdx.y * 32;
#pragma unroll
    for (int i = 0; i < 4; i++) {
        const float v = in[zoff + (size_t)(r0 + ty + i * 8) * C + c0 + tx];
        tl[ty + i * 8][tx] = v;
        if (out2) out2[zoff + (size_t)(r0 + ty + i * 8) * C + c0 + tx] = f2bf(v);
    }
    __syncthreads();
#pragma unroll
    for (int i = 0; i < 4; i++)
        out[zoff + (size_t)(c0 + ty + i * 8) * R + r0 + tx] = f2bf(tl[tx][ty + i * 8]);
}

// ---------------------------------------------------------------------------
// MFMA GEMM core A (128x128 tile, BK=32) — used only by gate_gemm (fp32 A
// converted in staging). Padded LDS stride 40 ushorts. Proven in R3/R4.
// ---------------------------------------------------------------------------
#define GEMM_PREAMBLE()                                                        \
    __shared__ ushort_t As[128 * 40];                                          \
    __shared__ ushort_t Bs[128 * 40];                                          \
    const int t = threadIdx.x;                                                 \
    const int m0 = blockIdx.y * 128, n0 = blockIdx.x * 128;                    \
    const int sr = t >> 2;               /* 0..63 */                           \
    const int sc = (t & 3) * 8;          /* 0,8,16,24 */                       \
    const int lane = t & 63, w = t >> 6;                                       \
    const int wm = (w >> 1) * 64, wn = (w & 1) * 64;                           \
    const int fr = lane & 15, fq = lane >> 4;                                  \
    floatx4 acc[4][4];                                                         \
    _Pragma("unroll") for (int i = 0; i < 4; i++)                              \
        _Pragma("unroll") for (int j = 0; j < 4; j++) {                        \
            acc[i][j][0] = 0.f; acc[i][j][1] = 0.f;                            \
            acc[i][j][2] = 0.f; acc[i][j][3] = 0.f; }

#define GEMM_MFMA_STAGE()                                                      \
    short8 af[4], bfg[4];                                                      \
    _Pragma("unroll") for (int i = 0; i < 4; i++) {                            \
        af[i]  = *(const short8*)&As[(wm + i * 16 + fr) * 40 + fq * 8];        \
        bfg[i] = *(const short8*)&Bs[(wn + i * 16 + fr) * 40 + fq * 8];        \
    }                                                                          \
    _Pragma("unroll") for (int i = 0; i < 4; i++)                              \
        _Pragma("unroll") for (int j = 0; j < 4; j++)                          \
            acc[i][j] = __builtin_amdgcn_mfma_f32_16x16x32_bf16(               \
                af[i], bfg[j], acc[i][j], 0, 0, 0);

// Gate GEMM: A = concat(NX,CD) fp32 (convert in staging), B = WgT bf16 [512][1024]
// Epilogue: g = sigmoid(acc + bg); Fb = bf16(g*NX + (1-g)*CD).  M=BS,N=512,K=1024
__global__ __launch_bounds__(256) void gate_gemm(
    const float* __restrict__ NX, const float* __restrict__ CD,
    const ushort_t* __restrict__ WgT, const float* __restrict__ bg,
    ushort_t* __restrict__ Fb) {
    GEMM_PREAMBLE();
    const ushort_t* Bb = WgT + (size_t)n0 * 1024;

    for (int k0 = 0; k0 < 1024; k0 += 32) {
        const float* Asrc = (k0 < 512) ? NX : CD;
        const int kk = k0 & 511;
        const float* p0 = Asrc + (size_t)(m0 + sr) * 512 + kk + sc;
        const float* p1 = Asrc + (size_t)(m0 + sr + 64) * 512 + kk + sc;
        float4 f00 = *(const float4*)p0;       float4 f01 = *(const float4*)(p0 + 4);
        float4 f10 = *(const float4*)p1;       float4 f11 = *(const float4*)(p1 + 4);
        int4 b0 = *(const int4*)(Bb + (size_t)sr * 1024 + k0 + sc);
        int4 b1 = *(const int4*)(Bb + (size_t)(sr + 64) * 1024 + k0 + sc);
        short8 pa0 = pack8(f00, f01), pa1 = pack8(f10, f11);
        __syncthreads();
        *(short8*)&As[sr * 40 + sc] = pa0;
        *(short8*)&As[(sr + 64) * 40 + sc] = pa1;
        *(int4*)&Bs[sr * 40 + sc] = b0;
        *(int4*)&Bs[(sr + 64) * 40 + sc] = b1;
        __syncthreads();
        GEMM_MFMA_STAGE();
    }

#pragma unroll
    for (int i = 0; i < 4; i++) {
#pragma unroll
        for (int j = 0; j < 4; j++) {
#pragma unroll
            for (int r = 0; r < 4; r++) {
                const int m = m0 + wm + i * 16 + fq * 4 + r;
                const int n = n0 + wn + j * 16 + fr;
                const float z = acc[i][j][r] + bg[n];
                const float g = 1.f / (1.f + expf(-z));
                const size_t idx = (size_t)m * 512 + n;
                Fb[idx] = f2bf(g * NX[idx] + (1.f - g) * CD[idx]);
            }
        }
    }
}

// ---------------------------------------------------------------------------
// MFMA GEMM core C (128x128 tile, BK=64) — pure-bf16 qk/pv/ffn GEMMs.
// 4 waves (2x2), wave tile 64x64, 32 MFMA per barrier-pair per wave (4x the
// old 128x64/BK32 core). Padded LDS stride 72 ushorts (144 B: ds_read rows
// land 2-way max = free). LDS 36,864 B -> 4 blocks/CU LDS-limit.
// Staging: each thread 4x int4 per operand, lanes 0..7 cover one full row
// (128 B) contiguously -> perfectly coalesced 16 B/lane loads.
// ---------------------------------------------------------------------------
#define GEMM4_PREAMBLE()                                                       \
    __shared__ ushort_t As[128 * 72];                                          \
    __shared__ ushort_t Bs[128 * 72];                                          \
    const int t = threadIdx.x;                                                 \
    const int m0 = blockIdx.y * 128, n0 = blockIdx.x * 128;                    \
    const int sr8 = t >> 3;              /* 0..31 */                           \
    const int sc8 = (t & 7) * 8;         /* 0..56 shorts */                    \
    const int lane = t & 63, w = t >> 6;                                       \
    const int wm = (w >> 1) * 64, wn = (w & 1) * 64;                           \
    const int fr = lane & 15, fq = lane >> 4;                                  \
    floatx4 acc[4][4];                                                         \
    _Pragma("unroll") for (int i = 0; i < 4; i++)                              \
        _Pragma("unroll") for (int j = 0; j < 4; j++) {                        \
            acc[i][j][0] = 0.f; acc[i][j][1] = 0.f;                            \
            acc[i][j][2] = 0.f; acc[i][j][3] = 0.f; }

#define GEMM4_K_STEP(Ab, lda, Bb, ldb, k0)                                     \
    {                                                                          \
        int4 ra[4], rb[4];                                                     \
        _Pragma("unroll") for (int i = 0; i < 4; i++) {                        \
            ra[i] = *(const int4*)(Ab + (size_t)(sr8 + i * 32) * lda + k0 + sc8); \
            rb[i] = *(const int4*)(Bb + (size_t)(sr8 + i * 32) * ldb + k0 + sc8); \
        }                                                                      \
        __syncthreads();                                                       \
        _Pragma("unroll") for (int i = 0; i < 4; i++) {                        \
            *(int4*)&As[(sr8 + i * 32) * 72 + sc8] = ra[i];                    \
            *(int4*)&Bs[(sr8 + i * 32) * 72 + sc8] = rb[i];                    \
        }                                                                      \
        __syncthreads();                                                       \
        _Pragma("unroll") for (int kk = 0; kk < 2; kk++) {                     \
            short8 af[4], bfg[4];                                              \
            _Pragma("unroll") for (int i = 0; i < 4; i++) {                    \
                af[i]  = *(const short8*)&As[(wm + i * 16 + fr) * 72 + kk * 32 + fq * 8]; \
                bfg[i] = *(const short8*)&Bs[(wn + i * 16 + fr) * 72 + kk * 32 + fq * 8]; \
            }                                                                  \
            _Pragma("unroll") for (int i = 0; i < 4; i++)                      \
                _Pragma("unroll") for (int j = 0; j < 4; j++)                  \
                    acc[i][j] = __builtin_amdgcn_mfma_f32_16x16x32_bf16(       \
                        af[i], bfg[j], acc[i][j], 0, 0, 0);                    \
        }                                                                      \
    }

// EPI: 0 = scale + bf16 store; 1 = +bias, exact gelu, bf16 store;
//      2 = fp32 accumulate in place (T += acc [+ bias if init])
template <int EPI>
__global__ __launch_bounds__(256) void gemm4_std(
    const ushort_t* __restrict__ A, int lda, long sAz,
    const ushort_t* __restrict__ Bt, int ldb, long sBz,
    void* __restrict__ Cv, int ldc, long sCz,
    int K, const float* __restrict__ bias, float scale, int init) {
    GEMM4_PREAMBLE();
    const ushort_t* Ab = A + (size_t)blockIdx.z * sAz + (size_t)m0 * lda;
    const ushort_t* Bb = Bt + (size_t)blockIdx.z * sBz + (size_t)n0 * ldb;

    for (int k0 = 0; k0 < K; k0 += 64) {
        GEMM4_K_STEP(Ab, lda, Bb, ldb, k0);
    }

#pragma unroll
    for (int i = 0; i < 4; i++) {
#pragma unroll
        for (int j = 0; j < 4; j++) {
#pragma unroll
            for (int r = 0; r < 4; r++) {
                const int m = m0 + wm + i * 16 + fq * 4 + r;
                const int n = n0 + wn + j * 16 + fr;
                float v = acc[i][j][r];
                if (EPI == 0) {
                    ushort_t* C = (ushort_t*)Cv + (size_t)blockIdx.z * sCz;
                    C[(size_t)m * ldc + n] = f2bf(v * scale);
                } else if (EPI == 1) {
                    const float x = v + bias[n];
                    const float gl = 0.5f * x * (1.f + erff(x * 0.70710678118654752f));
                    ushort_t* C = (ushort_t*)Cv;
                    C[(size_t)m * ldc + n] = f2bf(gl);
                } else {
                    float* T = (float*)Cv;
                    const size_t idx = (size_t)m * ldc + n;
                    T[idx] = T[idx] + v + (init ? bias[n] : 0.f);
                }
            }
        }
    }
}

// ---------------------------------------------------------------------------
// Softmax over bf16 rows of 2048, in place
// ---------------------------------------------------------------------------
__global__ __launch_bounds__(256) void softmax_bf16(ushort_t* __restrict__ Sc) {
    __shared__ float sm[4];
    ushort_t* row = Sc + (size_t)blockIdx.x * 2048;
    const int t = threadIdx.x;
    ushort_t raw[8];
    *(int4*)raw = *(const int4*)(row + t * 8);
    float e[8];
    float mx = -1e30f;
#pragma unroll
    for (int j = 0; j < 8; j++) { e[j] = bf2f(raw[j]); mx = fmaxf(mx, e[j]); }
    mx = blk_reduce_max(mx, sm);
    float s = 0.f;
#pragma unroll
    for (int j = 0; j < 8; j++) { e[j] = expf(e[j] - mx); s += e[j]; }
    s = blk_reduce_sum(s, sm);
    const float inv = 1.f / s;
#pragma unroll
    for (int j = 0; j < 8; j++) raw[j] = f2bf(e[j] * inv);
    *(int4*)(row + t * 8) = *(const int4*)raw;
}

// ---------------------------------------------------------------------------
// LN1: q = LN(fused + attn) -> qf (fp32) and qb (bf16)
// ---------------------------------------------------------------------------
__global__ __launch_bounds__(256) void ln1_kernel(
    const ushort_t* __restrict__ Fb, const ushort_t* __restrict__ Ab,
    const float* __restrict__ g1, const float* __restrict__ be1,
    float* __restrict__ qf, ushort_t* __restrict__ qb) {
    __shared__ float sm[4];
    const size_t base = (size_t)blockIdx.x * 512;
    const int t = threadIdx.x;
    const float v0 = bf2f(Fb[base + t]) + bf2f(Ab[base + t]);
    const float v1 = bf2f(Fb[base + t + 256]) + bf2f(Ab[base + t + 256]);
    const float mu = blk_reduce_sum(v0 + v1, sm) * (1.f / 512.f);
    const float d0 = v0 - mu, d1 = v1 - mu;
    const float var = blk_reduce_sum(d0 * d0 + d1 * d1, sm) * (1.f / 512.f);
    const float rs = rsqrtf(var + LN_EPS);
    const float y0 = d0 * rs * g1[t] + be1[t];
    const float y1 = d1 * rs * g1[t + 256] + be1[t + 256];
    qf[base + t] = y0;          qf[base + t + 256] = y1;
    qb[base + t] = f2bf(y0);    qb[base + t + 256] = f2bf(y1);
}

// Final LN in place on fp32
__global__ __launch_bounds__(256) void ln2_kernel(
    float* __restrict__ T, const float* __restrict__ g,
    const float* __restrict__ be) {
    __shared__ float sm[4];
    const size_t base = (size_t)blockIdx.x * 512;
    const int t = threadIdx.x;
    const float v0 = T[base + t];
    const float v1 = T[base + t + 256];
    const float mu = blk_reduce_sum(v0 + v1, sm) * (1.f / 512.f);
    const float d0 = v0 - mu, d1 = v1 - mu;
    const float var = blk_reduce_sum(d0 * d0 + d1 * d1, sm) * (1.f / 512.f);
    const float rs = rsqrtf(var + LN_EPS);
    T[base + t] = d0 * rs * g[t] + be[t];
    T[base + t + 256] = d1 * rs * g[t + 256] + be[t + 256];
}

// ---------------------------------------------------------------------------
extern "C" void kernel_launch(void* const* d_in, const int* in_sizes, int n_in,
                              void* d_out, int out_size, void* d_ws, size_t ws_size,
                              hipStream_t stream) {
    const float* NX  = (const float*)d_in[0];
    const float* X   = (const float*)d_in[1];
    const float* CD  = (const float*)d_in[2];
    const float* Wg  = (const float*)d_in[3];
    const float* bg  = (const float*)d_in[4];
    const float* W1  = (const float*)d_in[5];
    const float* b1  = (const float*)d_in[6];
    const float* W2  = (const float*)d_in[7];
    const float* b2  = (const float*)d_in[8];
    const float* g1  = (const float*)d_in[9];
    const float* be1 = (const float*)d_in[10];
    const float* g2  = (const float*)d_in[11];
    const float* be2 = (const float*)d_in[12];

    // ws: 3 slots x 16,777,216 B = 50,331,648 B (proven-safe since R2)
    // slot0: Xb -> attnb (progressive, see R6 note) -> hbuf
    // slot1: Fb -> W1T/W2T;  slot2: WgT -> XbT -> qb
    // d_out: scores (bf16) -> qf (fp32, final)
    ushort_t* slot0 = (ushort_t*)d_ws;
    ushort_t* slot1 = (ushort_t*)((char*)d_ws + 16777216);
    ushort_t* slot2 = (ushort_t*)((char*)d_ws + 33554432);
    ushort_t* Xb    = slot0;                    // [8][2048][512] bf16
    ushort_t* attnb = slot0;
    ushort_t* hbuf  = slot0;
    ushort_t* Fb    = slot1;
    ushort_t* W1T   = slot1;                    // [1024][512] bf16, 1 MB
    ushort_t* W2T   = slot1 + 524288;           // [512][1024] bf16, 1 MB
    ushort_t* WgT   = slot2;                    // [512][1024] bf16, 1 MB
    ushort_t* XbT   = slot2;                    // [8][512][2048] bf16, 16.78 MB
    ushort_t* qb    = slot2;                    // [BS][512] bf16
    ushort_t* Scb   = (ushort_t*)d_out;         // 4 batches [S][S] bf16
    float*    qf    = (float*)d_out;

    // 1) Wg^T (slot2)
    transpose_cvt<<<dim3(512 / 32, 1024 / 32, 1), 256, 0, stream>>>(
        Wg, WgT, 1024, 512, nullptr);

    // 2) gated fusion -> Fb (128x128 BK32 core; fp32 A converted in staging)
    gate_gemm<<<dim3(4, 128), 256, 0, stream>>>(NX, CD, WgT, bg, Fb);

    // 3) X^T per batch into slot2 (WgT dead) — needed by PV;
    //    fused straight bf16 copy Xb into slot0 — needed by QK
    transpose_cvt<<<dim3(512 / 32, 2048 / 32, 8), 256, 0, stream>>>(
        X, XbT, 2048, 512, Xb);

    // 4) attention in 2 groups of 4 batches; scores in d_out
    for (int g = 0; g < 2; g++) {
        const size_t go = (size_t)g * 4 * S * 512;
        // QK: Sc = (Fb @ Xb^T) * scale   (A and B both row-major [seq][512])
        gemm4_std<0><<<dim3(16, 16, 4), 256, 0, stream>>>(
            Fb + go, D, (long)S * D,
            Xb + go, D, (long)S * D,
            (void*)Scb, S, (long)S * S, D, nullptr, ATTN_SCALE, 0);
        softmax_bf16<<<4 * S, 256, 0, stream>>>(Scb);
        // PV: attn = P @ X  (Bt = X^T [512][2048])
        gemm4_std<0><<<dim3(4, 16, 4), 256, 0, stream>>>(
            Scb, S, (long)S * S,
            XbT + go, S, (long)D * S,
            (void*)(attnb + go), 512, (long)S * 512, S, nullptr, 1.f, 0);
    }

    // 5) q = LN(fused + attn): qf -> d_out (scores dead), qb -> slot2 (XbT dead)
    ln1_kernel<<<BS, 256, 0, stream>>>(Fb, attnb, g1, be1, qf, qb);

    // 6) weight transposes into slot1 (Fb dead after LN1)
    transpose_cvt<<<dim3(1024 / 32, 512 / 32, 1), 256, 0, stream>>>(
        W1, W1T, 512, 1024, nullptr);
    transpose_cvt<<<dim3(512 / 32, 1024 / 32, 1), 256, 0, stream>>>(
        W2, W2T, 1024, 512, nullptr);

    // 7) FFN in 2 halves; hidden half in slot0 (attnb dead); t accumulates in d_out
    for (int h = 0; h < 2; h++) {
        gemm4_std<1><<<dim3(4, 128), 256, 0, stream>>>(
            qb, 512, 0, W1T + (size_t)h * 512 * 512, 512, 0,
            (void*)hbuf, 512, 0, 512, b1 + h * 512, 1.f, 0);
        gemm4_std<2><<<dim3(4, 128), 256, 0, stream>>>(
            hbuf, 512, 0, W2T + h * 512, 1024, 0,
            (void*)qf, 512, 0, 512, b2, 1.f, h == 0 ? 1 : 0);
    }

    // 8) out = LN(t) in place in d_out
    ln2_kernel<<<BS, 256, 0, stream>>>(qf, g2, be2);
}

// Round 2
// 545.277 us; speedup vs baseline: 1.5555x; 1.5555x over previous
//
#include <hip/hip_runtime.h>
#include <math.h>

typedef unsigned short ushort_t;
typedef unsigned int uint_t;
typedef __attribute__((ext_vector_type(8))) short short8;
typedef __attribute__((ext_vector_type(4))) float floatx4;

// Problem dims
constexpr int B = 8;
constexpr int S = 2048;
constexpr int D = 512;
constexpr int BS = B * S;          // 16384 rows
constexpr float LN_EPS = 1e-5f;
constexpr float ATTN_SCALE = 0.04419417382415922f;  // 1/sqrt(512)

// R5 lesson (post-timing absmax 4.0, dur unchanged): global_load_lds staging
// on this toolchain gave 0 speedup and corrupted post-warm replays -> reverted
// to R4's proven padded-LDS VGPR staging. Also: do NOT alias Fb onto CDb/NXb —
// the gate epilogue of a fast n-block clobbers A-tiles still being staged by
// sibling n-blocks of the same m-range (cross-block race).
// R6 lesson (848 us, MfmaUtil 6.7%, VALU 6.2%, Occ 10.8% on PV): 128x128/BK=64
// tiles quartered block count on this grid-starved problem (PV: 256 blocks =
// 1 block/CU) -> single-buffered load->barrier->vmcnt chain fully exposed
// (~7k cy/K-step). Bigger tile without more TLP or in-block pipelining loses.
// R7: revert to gemm3 (128x64/BK=32, stride-40) + (a) prefetch reorder: next
// K-step loads issued AFTER barrier-2, BEFORE MFMA, so vmcnt wait lands at the
// NEXT iteration's LDS write (latency overlaps MFMA+barrier); (b) qk is pure
// bf16 via Xb (straight bf16 copy of X fused into the X-transpose kernel),
// removing the pack8 VALU tax from qk staging.
// Xb aliasing: Xb lives in slot0 and is consumed group-by-group exactly as
// attnb (pv output) overwrites it: pv g0 writes batches 0-3 only after qk g0
// read them; qk g1 reads batches 4-7 which pv hasn't touched. Stream-ordered.

// ---------------------------------------------------------------------------
// bf16 helpers (RNE)
// ---------------------------------------------------------------------------
__device__ __forceinline__ ushort_t f2bf(float f) {
    union { float f; uint_t u; } x; x.f = f;
    uint_t r = x.u + 0x7fffu + ((x.u >> 16) & 1u);
    return (ushort_t)(r >> 16);
}
__device__ __forceinline__ float bf2f(ushort_t h) {
    union { uint_t u; float f; } y; y.u = ((uint_t)h) << 16;
    return y.f;
}
__device__ __forceinline__ short8 pack8(float4 a, float4 b) {
    short8 p;
    p[0] = (short)f2bf(a.x); p[1] = (short)f2bf(a.y);
    p[2] = (short)f2bf(a.z); p[3] = (short)f2bf(a.w);
    p[4] = (short)f2bf(b.x); p[5] = (short)f2bf(b.y);
    p[6] = (short)f2bf(b.z); p[7] = (short)f2bf(b.w);
    return p;
}

// ---------------------------------------------------------------------------
// Reductions (256-thread blocks = 4 waves of 64)
// ---------------------------------------------------------------------------
__device__ __forceinline__ float blk_reduce_sum(float v, float* sm) {
#pragma unroll
    for (int o = 32; o; o >>= 1) v += __shfl_down(v, o, 64);
    __syncthreads();
    if ((threadIdx.x & 63) == 0) sm[threadIdx.x >> 6] = v;
    __syncthreads();
    return sm[0] + sm[1] + sm[2] + sm[3];
}
__device__ __forceinline__ float blk_reduce_max(float v, float* sm) {
#pragma unroll
    for (int o = 32; o; o >>= 1) v = fmaxf(v, __shfl_down(v, o, 64));
    __syncthreads();
    if ((threadIdx.x & 63) == 0) sm[threadIdx.x >> 6] = v;
    __syncthreads();
    return fmaxf(fmaxf(sm[0], sm[1]), fmaxf(sm[2], sm[3]));
}

// ---------------------------------------------------------------------------
// fp32 [R][C] -> bf16 [C][R] transpose+convert; batched via blockIdx.z (z*R*C)
// Optionally also emits the straight (non-transposed) bf16 copy into out2.
// ---------------------------------------------------------------------------
__global__ __launch_bounds__(256) void transpose_cvt(
    const float* __restrict__ in, ushort_t* __restrict__ out, int R, int C,
    ushort_t* __restrict__ out2) {
    __shared__ float tl[32][33];
    const size_t zoff = (size_t)blockIdx.z * R * C;
    const int tx = threadIdx.x & 31, ty = threadIdx.x >> 5;  // ty 0..7
    const int c0 = blockIdx.x * 32, r0 = blockIdx.y * 32;
#pragma unroll
    for (int i = 0; i < 4; i++) {
        const float v = in[zoff + (size_t)(r0 + ty + i * 8) * C + c0 + tx];
        tl[ty + i * 8][tx] = v;
        if (out2) out2[zoff + (size_t)(r0 + ty + i * 8) * C + c0 + tx] = f2bf(v);
    }
    __syncthreads();
#pragma unroll
    for (int i = 0; i < 4; i++)
        out[zoff + (size_t)(c0 + ty + i * 8) * R + r0 + tx] = f2bf(tl[tx][ty + i * 8]);
}

// ---------------------------------------------------------------------------
// MFMA GEMM core A (128x128 tile, BK=32) — used only by gate_gemm (fp32 A
// converted in staging). Padded LDS stride 40 ushorts. Proven in R3/R4.
// ---------------------------------------------------------------------------
#define GEMM_PREAMBLE()                                                        \
    __shared__ ushort_t As[128 * 40];                                          \
    __shared__ ushort_t Bs[128 * 40];                                          \
    const int t = threadIdx.x;                                                 \
    const int m0 = blockIdx.y * 128, n0 = blockIdx.x * 128;                    \
    const int sr = t >> 2;               /* 0..63 */                           \
    const int sc = (t & 3) * 8;          /* 0,8,16,24 */                       \
    const int lane = t & 63, w = t >> 6;                                       \
    const int wm = (w >> 1) * 64, wn = (w & 1) * 64;                           \
    const int fr = lane & 15, fq = lane >> 4;                                  \
    floatx4 acc[4][4];                                                         \
    _Pragma("unroll") for (int i = 0; i < 4; i++)                              \
        _Pragma("unroll") for (int j = 0; j < 4; j++) {                        \
            acc[i][j][0] = 0.f; acc[i][j][1] = 0.f;                            \
            acc[i][j][2] = 0.f; acc[i][j][3] = 0.f; }

#define GEMM_MFMA_STAGE()                                                      \
    short8 af[4], bfg[4];                                                      \
    _Pragma("unroll") for (int i = 0; i < 4; i++) {                            \
        af[i]  = *(const short8*)&As[(wm + i * 16 + fr) * 40 + fq * 8];        \
        bfg[i] = *(const short8*)&Bs[(wn + i * 16 + fr) * 40 + fq * 8];        \
    }                                                                          \
    _Pragma("unroll") for (int i = 0; i < 4; i++)                              \
        _Pragma("unroll") for (int j = 0; j < 4; j++)                          \
            acc[i][j] = __builtin_amdgcn_mfma_f32_16x16x32_bf16(               \
                af[i], bfg[j], acc[i][j], 0, 0, 0);

// Gate GEMM: A = concat(NX,CD) fp32 (convert in staging), B = WgT bf16 [512][1024]
// Epilogue: g = sigmoid(acc + bg); Fb = bf16(g*NX + (1-g)*CD).  M=BS,N=512,K=1024
// R7: prefetched — next-step loads issue before the MFMA stage.
__global__ __launch_bounds__(256) void gate_gemm(
    const float* __restrict__ NX, const float* __restrict__ CD,
    const ushort_t* __restrict__ WgT, const float* __restrict__ bg,
    ushort_t* __restrict__ Fb) {
    GEMM_PREAMBLE();
    const ushort_t* Bb = WgT + (size_t)n0 * 1024;

    // prologue: k0 = 0 (Asrc = NX)
    float4 f00, f01, f10, f11;
    int4 b0, b1;
    {
        const float* p0 = NX + (size_t)(m0 + sr) * 512 + sc;
        const float* p1 = NX + (size_t)(m0 + sr + 64) * 512 + sc;
        f00 = *(const float4*)p0;  f01 = *(const float4*)(p0 + 4);
        f10 = *(const float4*)p1;  f11 = *(const float4*)(p1 + 4);
        b0 = *(const int4*)(Bb + (size_t)sr * 1024 + sc);
        b1 = *(const int4*)(Bb + (size_t)(sr + 64) * 1024 + sc);
    }

    for (int k0 = 0; k0 < 1024; k0 += 32) {
        __syncthreads();
        short8 pa0 = pack8(f00, f01), pa1 = pack8(f10, f11);
        *(short8*)&As[sr * 40 + sc] = pa0;
        *(short8*)&As[(sr + 64) * 40 + sc] = pa1;
        *(int4*)&Bs[sr * 40 + sc] = b0;
        *(int4*)&Bs[(sr + 64) * 40 + sc] = b1;
        __syncthreads();
        const int kn = k0 + 32;
        if (kn < 1024) {
            const float* Asrc = (kn < 512) ? NX : CD;
            const int kk = kn & 511;
            const float* p0 = Asrc + (size_t)(m0 + sr) * 512 + kk + sc;
            const float* p1 = Asrc + (size_t)(m0 + sr + 64) * 512 + kk + sc;
            f00 = *(const float4*)p0;  f01 = *(const float4*)(p0 + 4);
            f10 = *(const float4*)p1;  f11 = *(const float4*)(p1 + 4);
            b0 = *(const int4*)(Bb + (size_t)sr * 1024 + kn + sc);
            b1 = *(const int4*)(Bb + (size_t)(sr + 64) * 1024 + kn + sc);
        }
        GEMM_MFMA_STAGE();
    }

#pragma unroll
    for (int i = 0; i < 4; i++) {
#pragma unroll
        for (int j = 0; j < 4; j++) {
#pragma unroll
            for (int r = 0; r < 4; r++) {
                const int m = m0 + wm + i * 16 + fq * 4 + r;
                const int n = n0 + wn + j * 16 + fr;
                const float z = acc[i][j][r] + bg[n];
                const float g = 1.f / (1.f + expf(-z));
                const size_t idx = (size_t)m * 512 + n;
                Fb[idx] = f2bf(g * NX[idx] + (1.f - g) * CD[idx]);
            }
        }
    }
}

// ---------------------------------------------------------------------------
// MFMA GEMM core B (128x64 tile, BK=32) — qk/pv/ffn. Higher grid occupancy
// for the grid-starved GEMMs. 4 waves stacked on M (wave tile 32x64),
// 8 MFMA/stage, LDS 15,360 B, acc 32 VGPR. Proven at 555 us (R4/R5).
// R7: prefetched K-loop (see header note).
// ---------------------------------------------------------------------------
#define GEMM3_PREAMBLE()                                                       \
    __shared__ ushort_t As[128 * 40];                                          \
    __shared__ ushort_t Bs[64 * 40];                                           \
    const int t = threadIdx.x;                                                 \
    const int m0 = blockIdx.y * 128, n0 = blockIdx.x * 64;                     \
    const int sr = t >> 2;               /* 0..63 */                           \
    const int sc = (t & 3) * 8;          /* 0,8,16,24 */                       \
    const int lane = t & 63, w = t >> 6;                                       \
    const int wm = w * 32;                                                     \
    const int fr = lane & 15, fq = lane >> 4;                                  \
    floatx4 acc[2][4];                                                         \
    _Pragma("unroll") for (int i = 0; i < 2; i++)                              \
        _Pragma("unroll") for (int j = 0; j < 4; j++) {                        \
            acc[i][j][0] = 0.f; acc[i][j][1] = 0.f;                            \
            acc[i][j][2] = 0.f; acc[i][j][3] = 0.f; }

#define GEMM3_MFMA_STAGE()                                                     \
    short8 af[2], bfg[4];                                                      \
    _Pragma("unroll") for (int i = 0; i < 2; i++)                              \
        af[i]  = *(const short8*)&As[(wm + i * 16 + fr) * 40 + fq * 8];        \
    _Pragma("unroll") for (int j = 0; j < 4; j++)                              \
        bfg[j] = *(const short8*)&Bs[(j * 16 + fr) * 40 + fq * 8];             \
    _Pragma("unroll") for (int i = 0; i < 2; i++)                              \
        _Pragma("unroll") for (int j = 0; j < 4; j++)                          \
            acc[i][j] = __builtin_amdgcn_mfma_f32_16x16x32_bf16(               \
                af[i], bfg[j], acc[i][j], 0, 0, 0);

// EPI: 0 = scale + bf16 store; 1 = +bias, exact gelu, bf16 store;
//      2 = fp32 accumulate in place (T += acc [+ bias if init])
template <int EPI>
__global__ __launch_bounds__(256) void gemm3_std(
    const ushort_t* __restrict__ A, int lda, long sAz,
    const ushort_t* __restrict__ Bt, int ldb, long sBz,
    void* __restrict__ Cv, int ldc, long sCz,
    int K, const float* __restrict__ bias, float scale, int init) {
    GEMM3_PREAMBLE();
    const ushort_t* Ab = A + (size_t)blockIdx.z * sAz + (size_t)m0 * lda;
    const ushort_t* Bb = Bt + (size_t)blockIdx.z * sBz + (size_t)n0 * ldb;

    // prologue: k0 = 0
    int4 a0 = *(const int4*)(Ab + (size_t)sr * lda + sc);
    int4 a1 = *(const int4*)(Ab + (size_t)(sr + 64) * lda + sc);
    int4 b0 = *(const int4*)(Bb + (size_t)sr * ldb + sc);

    for (int k0 = 0; k0 < K; k0 += 32) {
        __syncthreads();
        *(int4*)&As[sr * 40 + sc] = a0;
        *(int4*)&As[(sr + 64) * 40 + sc] = a1;
        *(int4*)&Bs[sr * 40 + sc] = b0;
        __syncthreads();
        const int kn = k0 + 32;
        if (kn < K) {
            a0 = *(const int4*)(Ab + (size_t)sr * lda + kn + sc);
            a1 = *(const int4*)(Ab + (size_t)(sr + 64) * lda + kn + sc);
            b0 = *(const int4*)(Bb + (size_t)sr * ldb + kn + sc);
        }
        GEMM3_MFMA_STAGE();
    }

#pragma unroll
    for (int i = 0; i < 2; i++) {
#pragma unroll
        for (int j = 0; j < 4; j++) {
#pragma unroll
            for (int r = 0; r < 4; r++) {
                const int m = m0 + wm + i * 16 + fq * 4 + r;
                const int n = n0 + j * 16 + fr;
                float v = acc[i][j][r];
                if (EPI == 0) {
                    ushort_t* C = (ushort_t*)Cv + (size_t)blockIdx.z * sCz;
                    C[(size_t)m * ldc + n] = f2bf(v * scale);
                } else if (EPI == 1) {
                    const float x = v + bias[n];
                    const float gl = 0.5f * x * (1.f + erff(x * 0.70710678118654752f));
                    ushort_t* C = (ushort_t*)Cv;
                    C[(size_t)m * ldc + n] = f2bf(gl);
                } else {
                    float* T = (float*)Cv;
                    const size_t idx = (size_t)m * ldc + n;
                    T[idx] = T[idx] + v + (init ? bias[n] : 0.f);
                }
            }
        }
    }
}

// ---------------------------------------------------------------------------
// Softmax over bf16 rows of 2048, in place
// ---------------------------------------------------------------------------
__global__ __launch_bounds__(256) void softmax_bf16(ushort_t* __restrict__ Sc) {
    __shared__ float sm[4];
    ushort_t* row = Sc + (size_t)blockIdx.x * 2048;
    const int t = threadIdx.x;
    ushort_t raw[8];
    *(int4*)raw = *(const int4*)(row + t * 8);
    float e[8];
    float mx = -1e30f;
#pragma unroll
    for (int j = 0; j < 8; j++) { e[j] = bf2f(raw[j]); mx = fmaxf(mx, e[j]); }
    mx = blk_reduce_max(mx, sm);
    float s = 0.f;
#pragma unroll
    for (int j = 0; j < 8; j++) { e[j] = expf(e[j] - mx); s += e[j]; }
    s = blk_reduce_sum(s, sm);
    const float inv = 1.f / s;
#pragma unroll
    for (int j = 0; j < 8; j++) raw[j] = f2bf(e[j] * inv);
    *(int4*)(row + t * 8) = *(const int4*)raw;
}

// ---------------------------------------------------------------------------
// LN1: q = LN(fused + attn) -> qf (fp32) and qb (bf16)
// ---------------------------------------------------------------------------
__global__ __launch_bounds__(256) void ln1_kernel(
    const ushort_t* __restrict__ Fb, const ushort_t* __restrict__ Ab,
    const float* __restrict__ g1, const float* __restrict__ be1,
    float* __restrict__ qf, ushort_t* __restrict__ qb) {
    __shared__ float sm[4];
    const size_t base = (size_t)blockIdx.x * 512;
    const int t = threadIdx.x;
    const float v0 = bf2f(Fb[base + t]) + bf2f(Ab[base + t]);
    const float v1 = bf2f(Fb[base + t + 256]) + bf2f(Ab[base + t + 256]);
    const float mu = blk_reduce_sum(v0 + v1, sm) * (1.f / 512.f);
    const float d0 = v0 - mu, d1 = v1 - mu;
    const float var = blk_reduce_sum(d0 * d0 + d1 * d1, sm) * (1.f / 512.f);
    const float rs = rsqrtf(var + LN_EPS);
    const float y0 = d0 * rs * g1[t] + be1[t];
    const float y1 = d1 * rs * g1[t + 256] + be1[t + 256];
    qf[base + t] = y0;          qf[base + t + 256] = y1;
    qb[base + t] = f2bf(y0);    qb[base + t + 256] = f2bf(y1);
}

// Final LN in place on fp32
__global__ __launch_bounds__(256) void ln2_kernel(
    float* __restrict__ T, const float* __restrict__ g,
    const float* __restrict__ be) {
    __shared__ float sm[4];
    const size_t base = (size_t)blockIdx.x * 512;
    const int t = threadIdx.x;
    const float v0 = T[base + t];
    const float v1 = T[base + t + 256];
    const float mu = blk_reduce_sum(v0 + v1, sm) * (1.f / 512.f);
    const float d0 = v0 - mu, d1 = v1 - mu;
    const float var = blk_reduce_sum(d0 * d0 + d1 * d1, sm) * (1.f / 512.f);
    const float rs = rsqrtf(var + LN_EPS);
    T[base + t] = d0 * rs * g[t] + be[t];
    T[base + t + 256] = d1 * rs * g[t + 256] + be[t + 256];
}

// ---------------------------------------------------------------------------
extern "C" void kernel_launch(void* const* d_in, const int* in_sizes, int n_in,
                              void* d_out, int out_size, void* d_ws, size_t ws_size,
                              hipStream_t stream) {
    const float* NX  = (const float*)d_in[0];
    const float* X   = (const float*)d_in[1];
    const float* CD  = (const float*)d_in[2];
    const float* Wg  = (const float*)d_in[3];
    const float* bg  = (const float*)d_in[4];
    const float* W1  = (const float*)d_in[5];
    const float* b1  = (const float*)d_in[6];
    const float* W2  = (const float*)d_in[7];
    const float* b2  = (const float*)d_in[8];
    const float* g1  = (const float*)d_in[9];
    const float* be1 = (const float*)d_in[10];
    const float* g2  = (const float*)d_in[11];
    const float* be2 = (const float*)d_in[12];

    // ws: 3 slots x 16,777,216 B = 50,331,648 B (proven-safe since R2)
    // slot0: Xb -> attnb (progressive, see header note) -> hbuf
    // slot1: Fb -> W1T/W2T;  slot2: WgT -> XbT -> qb
    // d_out: scores (bf16) -> qf (fp32, final)
    ushort_t* slot0 = (ushort_t*)d_ws;
    ushort_t* slot1 = (ushort_t*)((char*)d_ws + 16777216);
    ushort_t* slot2 = (ushort_t*)((char*)d_ws + 33554432);
    ushort_t* Xb    = slot0;                    // [8][2048][512] bf16
    ushort_t* attnb = slot0;
    ushort_t* hbuf  = slot0;
    ushort_t* Fb    = slot1;
    ushort_t* W1T   = slot1;                    // [1024][512] bf16, 1 MB
    ushort_t* W2T   = slot1 + 524288;           // [512][1024] bf16, 1 MB
    ushort_t* WgT   = slot2;                    // [512][1024] bf16, 1 MB
    ushort_t* XbT   = slot2;                    // [8][512][2048] bf16, 16.78 MB
    ushort_t* qb    = slot2;                    // [BS][512] bf16
    ushort_t* Scb   = (ushort_t*)d_out;         // 4 batches [S][S] bf16
    float*    qf    = (float*)d_out;

    // 1) Wg^T (slot2)
    transpose_cvt<<<dim3(512 / 32, 1024 / 32, 1), 256, 0, stream>>>(
        Wg, WgT, 1024, 512, nullptr);

    // 2) gated fusion -> Fb (128x128 BK32 core; fp32 A converted in staging)
    gate_gemm<<<dim3(4, 128), 256, 0, stream>>>(NX, CD, WgT, bg, Fb);

    // 3) X^T per batch into slot2 (WgT dead) — needed by PV;
    //    fused straight bf16 copy Xb into slot0 — needed by QK
    transpose_cvt<<<dim3(512 / 32, 2048 / 32, 8), 256, 0, stream>>>(
        X, XbT, 2048, 512, Xb);

    // 4) attention in 2 groups of 4 batches; scores in d_out
    for (int g = 0; g < 2; g++) {
        const size_t go = (size_t)g * 4 * S * 512;
        // QK: Sc = (Fb @ Xb^T) * scale (pure bf16; A,Bt both row-major [seq][512])
        gemm3_std<0><<<dim3(32, 16, 4), 256, 0, stream>>>(
            Fb + go, D, (long)S * D,
            Xb + go, D, (long)S * D,
            (void*)Scb, S, (long)S * S, D, nullptr, ATTN_SCALE, 0);
        softmax_bf16<<<4 * S, 256, 0, stream>>>(Scb);
        // PV: attn = P @ X  (Bt = X^T [512][2048])
        gemm3_std<0><<<dim3(8, 16, 4), 256, 0, stream>>>(
            Scb, S, (long)S * S,
            XbT + go, S, (long)D * S,
            (void*)(attnb + go), 512, (long)S * 512, S, nullptr, 1.f, 0);
    }

    // 5) q = LN(fused + attn): qf -> d_out (scores dead), qb -> slot2 (XbT dead)
    ln1_kernel<<<BS, 256, 0, stream>>>(Fb, attnb, g1, be1, qf, qb);

    // 6) weight transposes into slot1 (Fb dead after LN1)
    transpose_cvt<<<dim3(1024 / 32, 512 / 32, 1), 256, 0, stream>>>(
        W1, W1T, 512, 1024, nullptr);
    transpose_cvt<<<dim3(512 / 32, 1024 / 32, 1), 256, 0, stream>>>(
        W2, W2T, 1024, 512, nullptr);

    // 7) FFN in 2 halves; hidden half in slot0 (attnb dead); t accumulates in d_out
    for (int h = 0; h < 2; h++) {
        gemm3_std<1><<<dim3(8, 128), 256, 0, stream>>>(
            qb, 512, 0, W1T + (size_t)h * 512 * 512, 512, 0,
            (void*)hbuf, 512, 0, 512, b1 + h * 512, 1.f, 0);
        gemm3_std<2><<<dim3(8, 128), 256, 0, stream>>>(
            hbuf, 512, 0, W2T + h * 512, 1024, 0,
            (void*)qf, 512, 0, 512, b2, 1.f, h == 0 ? 1 : 0);
    }

    // 8) out = LN(t) in place in d_out
    ln2_kernel<<<BS, 256, 0, stream>>>(qf, g2, be2);
}

// Round 3
// 538.960 us; speedup vs baseline: 1.5737x; 1.0117x over previous
//
#include <hip/hip_runtime.h>
#include <math.h>

typedef unsigned short ushort_t;
typedef unsigned int uint_t;
typedef __attribute__((ext_vector_type(8))) short short8;
typedef __attribute__((ext_vector_type(4))) float floatx4;

// Problem dims
constexpr int B = 8;
constexpr int S = 2048;
constexpr int D = 512;
constexpr int BS = B * S;          // 16384 rows
constexpr float LN_EPS = 1e-5f;
constexpr float ATTN_SCALE = 0.04419417382415922f;  // 1/sqrt(512)

// R5 lesson: global_load_lds staging corrupted post-warm replays on this
// toolchain -> VGPR reg-staging only. Do NOT alias Fb onto CDb/NXb.
// R6 lesson (848 us): 128x128/BK=64 quartered block count (PV 1 block/CU) ->
// latency fully exposed. Tile growth needs TLP or in-block pipelining.
// R7 lesson (545 us): prefetch-to-regs alone ~neutral — compiler already
// hoists; the serial cost is TWO barriers per K-step (stage->bar->mfma->bar).
// R8: single-barrier LDS double-buffer in all GEMM cores:
//   iter k: MFMA(buf[cur]) ; ds_write regs(k+1)->buf[cur^1] ; load k+2 ; bar
// Race audit: buf[cur^1] last read at iter k-1 (barrier at end of k-1
// separates); buf[cur] next written at iter k+1 (barrier at end of k
// separates). One barrier/iter is race-free. vmcnt wait lands at ds_write,
// one full iteration after load issue.
// qk/ffn additionally move to 128x128 dbuf core (gemm2: 16 MFMA/barrier/wave,
// grids stay >=2 blocks/CU: qk 1024 blocks, ffn 512). PV stays 128x64 (R6).
// Xb aliasing (slot0): qk g reads batches of Xb that pv g-1 hasn't
// overwritten; stream-ordered => safe.

// ---------------------------------------------------------------------------
// bf16 helpers (RNE)
// ---------------------------------------------------------------------------
__device__ __forceinline__ ushort_t f2bf(float f) {
    union { float f; uint_t u; } x; x.f = f;
    uint_t r = x.u + 0x7fffu + ((x.u >> 16) & 1u);
    return (ushort_t)(r >> 16);
}
__device__ __forceinline__ float bf2f(ushort_t h) {
    union { uint_t u; float f; } y; y.u = ((uint_t)h) << 16;
    return y.f;
}
__device__ __forceinline__ short8 pack8(float4 a, float4 b) {
    short8 p;
    p[0] = (short)f2bf(a.x); p[1] = (short)f2bf(a.y);
    p[2] = (short)f2bf(a.z); p[3] = (short)f2bf(a.w);
    p[4] = (short)f2bf(b.x); p[5] = (short)f2bf(b.y);
    p[6] = (short)f2bf(b.z); p[7] = (short)f2bf(b.w);
    return p;
}

// ---------------------------------------------------------------------------
// Reductions (256-thread blocks = 4 waves of 64)
// ---------------------------------------------------------------------------
__device__ __forceinline__ float blk_reduce_sum(float v, float* sm) {
#pragma unroll
    for (int o = 32; o; o >>= 1) v += __shfl_down(v, o, 64);
    __syncthreads();
    if ((threadIdx.x & 63) == 0) sm[threadIdx.x >> 6] = v;
    __syncthreads();
    return sm[0] + sm[1] + sm[2] + sm[3];
}
__device__ __forceinline__ float blk_reduce_max(float v, float* sm) {
#pragma unroll
    for (int o = 32; o; o >>= 1) v = fmaxf(v, __shfl_down(v, o, 64));
    __syncthreads();
    if ((threadIdx.x & 63) == 0) sm[threadIdx.x >> 6] = v;
    __syncthreads();
    return fmaxf(fmaxf(sm[0], sm[1]), fmaxf(sm[2], sm[3]));
}

// ---------------------------------------------------------------------------
// fp32 [R][C] -> bf16 [C][R] transpose+convert; batched via blockIdx.z (z*R*C)
// Optionally also emits the straight (non-transposed) bf16 copy into out2.
// ---------------------------------------------------------------------------
__global__ __launch_bounds__(256) void transpose_cvt(
    const float* __restrict__ in, ushort_t* __restrict__ out, int R, int C,
    ushort_t* __restrict__ out2) {
    __shared__ float tl[32][33];
    const size_t zoff = (size_t)blockIdx.z * R * C;
    const int tx = threadIdx.x & 31, ty = threadIdx.x >> 5;  // ty 0..7
    const int c0 = blockIdx.x * 32, r0 = blockIdx.y * 32;
#pragma unroll
    for (int i = 0; i < 4; i++) {
        const float v = in[zoff + (size_t)(r0 + ty + i * 8) * C + c0 + tx];
        tl[ty + i * 8][tx] = v;
        if (out2) out2[zoff + (size_t)(r0 + ty + i * 8) * C + c0 + tx] = f2bf(v);
    }
    __syncthreads();
#pragma unroll
    for (int i = 0; i < 4; i++)
        out[zoff + (size_t)(c0 + ty + i * 8) * R + r0 + tx] = f2bf(tl[tx][ty + i * 8]);
}

// ---------------------------------------------------------------------------
// Shared index preamble for 128-wide-M cores (4 waves)
// ---------------------------------------------------------------------------
#define IDX128()                                                               \
    const int t = threadIdx.x;                                                 \
    const int sr = t >> 2;               /* 0..63 */                           \
    const int sc = (t & 3) * 8;          /* 0,8,16,24 */                       \
    const int lane = t & 63, w = t >> 6;                                       \
    const int fr = lane & 15, fq = lane >> 4;

// MFMA stage from explicit LDS buffer pointers (128x128 core: 2x2 waves)
#define MFMA16(Asp, Bsp)                                                       \
    {                                                                          \
        short8 af[4], bfg[4];                                                  \
        _Pragma("unroll") for (int i = 0; i < 4; i++) {                        \
            af[i]  = *(const short8*)&(Asp)[(wm + i * 16 + fr) * 40 + fq * 8]; \
            bfg[i] = *(const short8*)&(Bsp)[(wn + i * 16 + fr) * 40 + fq * 8]; \
        }                                                                      \
        _Pragma("unroll") for (int i = 0; i < 4; i++)                          \
            _Pragma("unroll") for (int j = 0; j < 4; j++)                      \
                acc[i][j] = __builtin_amdgcn_mfma_f32_16x16x32_bf16(           \
                    af[i], bfg[j], acc[i][j], 0, 0, 0);                        \
    }

// MFMA stage for 128x64 core (4 waves stacked on M, wave tile 32x64)
#define MFMA8(Asp, Bsp)                                                        \
    {                                                                          \
        short8 af[2], bfg[4];                                                  \
        _Pragma("unroll") for (int i = 0; i < 2; i++)                          \
            af[i]  = *(const short8*)&(Asp)[(wm + i * 16 + fr) * 40 + fq * 8]; \
        _Pragma("unroll") for (int j = 0; j < 4; j++)                          \
            bfg[j] = *(const short8*)&(Bsp)[(j * 16 + fr) * 40 + fq * 8];      \
        _Pragma("unroll") for (int i = 0; i < 2; i++)                          \
            _Pragma("unroll") for (int j = 0; j < 4; j++)                      \
                acc[i][j] = __builtin_amdgcn_mfma_f32_16x16x32_bf16(           \
                    af[i], bfg[j], acc[i][j], 0, 0, 0);                        \
    }

// ---------------------------------------------------------------------------
// Gate GEMM: 128x128 tile, BK=32, double-buffered (R8).
// A = concat(NX,CD) fp32 (pack to bf16 at LDS-write time), B = WgT bf16.
// Epilogue: g = sigmoid(acc + bg); Fb = bf16(g*NX + (1-g)*CD). M=BS,N=512,K=1024
// ---------------------------------------------------------------------------
__global__ __launch_bounds__(256) void gate_gemm(
    const float* __restrict__ NX, const float* __restrict__ CD,
    const ushort_t* __restrict__ WgT, const float* __restrict__ bg,
    ushort_t* __restrict__ Fb) {
    __shared__ ushort_t As[2][128 * 40];
    __shared__ ushort_t Bs[2][128 * 40];
    IDX128();
    const int m0 = blockIdx.y * 128, n0 = blockIdx.x * 128;
    const int wm = (w >> 1) * 64, wn = (w & 1) * 64;
    floatx4 acc[4][4];
#pragma unroll
    for (int i = 0; i < 4; i++)
#pragma unroll
        for (int j = 0; j < 4; j++) {
            acc[i][j][0] = 0.f; acc[i][j][1] = 0.f;
            acc[i][j][2] = 0.f; acc[i][j][3] = 0.f;
        }
    const ushort_t* Bb = WgT + (size_t)n0 * 1024;

    float4 f00, f01, f10, f11;
    int4 b0, b1;
    // k = 0 (NX): load + write buf0
    {
        const float* p0 = NX + (size_t)(m0 + sr) * 512 + sc;
        const float* p1 = NX + (size_t)(m0 + sr + 64) * 512 + sc;
        f00 = *(const float4*)p0;  f01 = *(const float4*)(p0 + 4);
        f10 = *(const float4*)p1;  f11 = *(const float4*)(p1 + 4);
        b0 = *(const int4*)(Bb + (size_t)sr * 1024 + sc);
        b1 = *(const int4*)(Bb + (size_t)(sr + 64) * 1024 + sc);
        *(short8*)&As[0][sr * 40 + sc] = pack8(f00, f01);
        *(short8*)&As[0][(sr + 64) * 40 + sc] = pack8(f10, f11);
        *(int4*)&Bs[0][sr * 40 + sc] = b0;
        *(int4*)&Bs[0][(sr + 64) * 40 + sc] = b1;
    }
    // k = 32 (NX): load into regs
    {
        const float* p0 = NX + (size_t)(m0 + sr) * 512 + 32 + sc;
        const float* p1 = NX + (size_t)(m0 + sr + 64) * 512 + 32 + sc;
        f00 = *(const float4*)p0;  f01 = *(const float4*)(p0 + 4);
        f10 = *(const float4*)p1;  f11 = *(const float4*)(p1 + 4);
        b0 = *(const int4*)(Bb + (size_t)sr * 1024 + 32 + sc);
        b1 = *(const int4*)(Bb + (size_t)(sr + 64) * 1024 + 32 + sc);
    }
    __syncthreads();

    int cur = 0;
    for (int k0 = 0; k0 < 1024; k0 += 32) {
        MFMA16(As[cur], Bs[cur]);
        const int kn = k0 + 32;
        if (kn < 1024) {
            *(short8*)&As[cur ^ 1][sr * 40 + sc] = pack8(f00, f01);
            *(short8*)&As[cur ^ 1][(sr + 64) * 40 + sc] = pack8(f10, f11);
            *(int4*)&Bs[cur ^ 1][sr * 40 + sc] = b0;
            *(int4*)&Bs[cur ^ 1][(sr + 64) * 40 + sc] = b1;
            const int kf = kn + 32;
            if (kf < 1024) {
                const float* Asrc = (kf < 512) ? NX : CD;
                const int kk = kf & 511;
                const float* p0 = Asrc + (size_t)(m0 + sr) * 512 + kk + sc;
                const float* p1 = Asrc + (size_t)(m0 + sr + 64) * 512 + kk + sc;
                f00 = *(const float4*)p0;  f01 = *(const float4*)(p0 + 4);
                f10 = *(const float4*)p1;  f11 = *(const float4*)(p1 + 4);
                b0 = *(const int4*)(Bb + (size_t)sr * 1024 + kf + sc);
                b1 = *(const int4*)(Bb + (size_t)(sr + 64) * 1024 + kf + sc);
            }
        }
        __syncthreads();
        cur ^= 1;
    }

#pragma unroll
    for (int i = 0; i < 4; i++) {
#pragma unroll
        for (int j = 0; j < 4; j++) {
#pragma unroll
            for (int r = 0; r < 4; r++) {
                const int m = m0 + wm + i * 16 + fq * 4 + r;
                const int n = n0 + wn + j * 16 + fr;
                const float z = acc[i][j][r] + bg[n];
                const float g = 1.f / (1.f + expf(-z));
                const size_t idx = (size_t)m * 512 + n;
                Fb[idx] = f2bf(g * NX[idx] + (1.f - g) * CD[idx]);
            }
        }
    }
}

// ---------------------------------------------------------------------------
// gemm2: 128x128 tile, BK=32, pure bf16, double-buffered. For qk + ffn
// (grids >= 2 blocks/CU). LDS 40,960 B.
// EPI: 0 = scale + bf16 store; 1 = +bias, exact gelu, bf16 store;
//      2 = fp32 accumulate in place (T += acc [+ bias if init])
// ---------------------------------------------------------------------------
template <int EPI>
__global__ __launch_bounds__(256) void gemm2_std(
    const ushort_t* __restrict__ A, int lda, long sAz,
    const ushort_t* __restrict__ Bt, int ldb, long sBz,
    void* __restrict__ Cv, int ldc, long sCz,
    int K, const float* __restrict__ bias, float scale, int init) {
    __shared__ ushort_t As[2][128 * 40];
    __shared__ ushort_t Bs[2][128 * 40];
    IDX128();
    const int m0 = blockIdx.y * 128, n0 = blockIdx.x * 128;
    const int wm = (w >> 1) * 64, wn = (w & 1) * 64;
    floatx4 acc[4][4];
#pragma unroll
    for (int i = 0; i < 4; i++)
#pragma unroll
        for (int j = 0; j < 4; j++) {
            acc[i][j][0] = 0.f; acc[i][j][1] = 0.f;
            acc[i][j][2] = 0.f; acc[i][j][3] = 0.f;
        }
    const ushort_t* Ab = A + (size_t)blockIdx.z * sAz + (size_t)m0 * lda;
    const ushort_t* Bb = Bt + (size_t)blockIdx.z * sBz + (size_t)n0 * ldb;

    int4 a0 = *(const int4*)(Ab + (size_t)sr * lda + sc);
    int4 a1 = *(const int4*)(Ab + (size_t)(sr + 64) * lda + sc);
    int4 b0 = *(const int4*)(Bb + (size_t)sr * ldb + sc);
    int4 b1 = *(const int4*)(Bb + (size_t)(sr + 64) * ldb + sc);
    *(int4*)&As[0][sr * 40 + sc] = a0;
    *(int4*)&As[0][(sr + 64) * 40 + sc] = a1;
    *(int4*)&Bs[0][sr * 40 + sc] = b0;
    *(int4*)&Bs[0][(sr + 64) * 40 + sc] = b1;
    if (32 < K) {
        a0 = *(const int4*)(Ab + (size_t)sr * lda + 32 + sc);
        a1 = *(const int4*)(Ab + (size_t)(sr + 64) * lda + 32 + sc);
        b0 = *(const int4*)(Bb + (size_t)sr * ldb + 32 + sc);
        b1 = *(const int4*)(Bb + (size_t)(sr + 64) * ldb + 32 + sc);
    }
    __syncthreads();

    int cur = 0;
    for (int k0 = 0; k0 < K; k0 += 32) {
        MFMA16(As[cur], Bs[cur]);
        const int kn = k0 + 32;
        if (kn < K) {
            *(int4*)&As[cur ^ 1][sr * 40 + sc] = a0;
            *(int4*)&As[cur ^ 1][(sr + 64) * 40 + sc] = a1;
            *(int4*)&Bs[cur ^ 1][sr * 40 + sc] = b0;
            *(int4*)&Bs[cur ^ 1][(sr + 64) * 40 + sc] = b1;
            const int kf = kn + 32;
            if (kf < K) {
                a0 = *(const int4*)(Ab + (size_t)sr * lda + kf + sc);
                a1 = *(const int4*)(Ab + (size_t)(sr + 64) * lda + kf + sc);
                b0 = *(const int4*)(Bb + (size_t)sr * ldb + kf + sc);
                b1 = *(const int4*)(Bb + (size_t)(sr + 64) * ldb + kf + sc);
            }
        }
        __syncthreads();
        cur ^= 1;
    }

#pragma unroll
    for (int i = 0; i < 4; i++) {
#pragma unroll
        for (int j = 0; j < 4; j++) {
#pragma unroll
            for (int r = 0; r < 4; r++) {
                const int m = m0 + wm + i * 16 + fq * 4 + r;
                const int n = n0 + wn + j * 16 + fr;
                float v = acc[i][j][r];
                if (EPI == 0) {
                    ushort_t* C = (ushort_t*)Cv + (size_t)blockIdx.z * sCz;
                    C[(size_t)m * ldc + n] = f2bf(v * scale);
                } else if (EPI == 1) {
                    const float x = v + bias[n];
                    const float gl = 0.5f * x * (1.f + erff(x * 0.70710678118654752f));
                    ushort_t* C = (ushort_t*)Cv;
                    C[(size_t)m * ldc + n] = f2bf(gl);
                } else {
                    float* T = (float*)Cv;
                    const size_t idx = (size_t)m * ldc + n;
                    T[idx] = T[idx] + v + (init ? bias[n] : 0.f);
                }
            }
        }
    }
}

// ---------------------------------------------------------------------------
// gemm3: 128x64 tile, BK=32, double-buffered. For PV (512 blocks = 2/CU).
// LDS 30,720 B. 4 waves stacked on M (wave tile 32x64).
// ---------------------------------------------------------------------------
template <int EPI>
__global__ __launch_bounds__(256) void gemm3_std(
    const ushort_t* __restrict__ A, int lda, long sAz,
    const ushort_t* __restrict__ Bt, int ldb, long sBz,
    void* __restrict__ Cv, int ldc, long sCz,
    int K, const float* __restrict__ bias, float scale, int init) {
    __shared__ ushort_t As[2][128 * 40];
    __shared__ ushort_t Bs[2][64 * 40];
    IDX128();
    const int m0 = blockIdx.y * 128, n0 = blockIdx.x * 64;
    const int wm = w * 32;
    floatx4 acc[2][4];
#pragma unroll
    for (int i = 0; i < 2; i++)
#pragma unroll
        for (int j = 0; j < 4; j++) {
            acc[i][j][0] = 0.f; acc[i][j][1] = 0.f;
            acc[i][j][2] = 0.f; acc[i][j][3] = 0.f;
        }
    const ushort_t* Ab = A + (size_t)blockIdx.z * sAz + (size_t)m0 * lda;
    const ushort_t* Bb = Bt + (size_t)blockIdx.z * sBz + (size_t)n0 * ldb;

    int4 a0 = *(const int4*)(Ab + (size_t)sr * lda + sc);
    int4 a1 = *(const int4*)(Ab + (size_t)(sr + 64) * lda + sc);
    int4 b0 = *(const int4*)(Bb + (size_t)sr * ldb + sc);
    *(int4*)&As[0][sr * 40 + sc] = a0;
    *(int4*)&As[0][(sr + 64) * 40 + sc] = a1;
    *(int4*)&Bs[0][sr * 40 + sc] = b0;
    if (32 < K) {
        a0 = *(const int4*)(Ab + (size_t)sr * lda + 32 + sc);
        a1 = *(const int4*)(Ab + (size_t)(sr + 64) * lda + 32 + sc);
        b0 = *(const int4*)(Bb + (size_t)sr * ldb + 32 + sc);
    }
    __syncthreads();

    int cur = 0;
    for (int k0 = 0; k0 < K; k0 += 32) {
        MFMA8(As[cur], Bs[cur]);
        const int kn = k0 + 32;
        if (kn < K) {
            *(int4*)&As[cur ^ 1][sr * 40 + sc] = a0;
            *(int4*)&As[cur ^ 1][(sr + 64) * 40 + sc] = a1;
            *(int4*)&Bs[cur ^ 1][sr * 40 + sc] = b0;
            const int kf = kn + 32;
            if (kf < K) {
                a0 = *(const int4*)(Ab + (size_t)sr * lda + kf + sc);
                a1 = *(const int4*)(Ab + (size_t)(sr + 64) * lda + kf + sc);
                b0 = *(const int4*)(Bb + (size_t)sr * ldb + kf + sc);
            }
        }
        __syncthreads();
        cur ^= 1;
    }

#pragma unroll
    for (int i = 0; i < 2; i++) {
#pragma unroll
        for (int j = 0; j < 4; j++) {
#pragma unroll
            for (int r = 0; r < 4; r++) {
                const int m = m0 + wm + i * 16 + fq * 4 + r;
                const int n = n0 + j * 16 + fr;
                float v = acc[i][j][r];
                if (EPI == 0) {
                    ushort_t* C = (ushort_t*)Cv + (size_t)blockIdx.z * sCz;
                    C[(size_t)m * ldc + n] = f2bf(v * scale);
                } else if (EPI == 1) {
                    const float x = v + bias[n];
                    const float gl = 0.5f * x * (1.f + erff(x * 0.70710678118654752f));
                    ushort_t* C = (ushort_t*)Cv;
                    C[(size_t)m * ldc + n] = f2bf(gl);
                } else {
                    float* T = (float*)Cv;
                    const size_t idx = (size_t)m * ldc + n;
                    T[idx] = T[idx] + v + (init ? bias[n] : 0.f);
                }
            }
        }
    }
}

// ---------------------------------------------------------------------------
// Softmax over bf16 rows of 2048, in place
// ---------------------------------------------------------------------------
__global__ __launch_bounds__(256) void softmax_bf16(ushort_t* __restrict__ Sc) {
    __shared__ float sm[4];
    ushort_t* row = Sc + (size_t)blockIdx.x * 2048;
    const int t = threadIdx.x;
    ushort_t raw[8];
    *(int4*)raw = *(const int4*)(row + t * 8);
    float e[8];
    float mx = -1e30f;
#pragma unroll
    for (int j = 0; j < 8; j++) { e[j] = bf2f(raw[j]); mx = fmaxf(mx, e[j]); }
    mx = blk_reduce_max(mx, sm);
    float s = 0.f;
#pragma unroll
    for (int j = 0; j < 8; j++) { e[j] = expf(e[j] - mx); s += e[j]; }
    s = blk_reduce_sum(s, sm);
    const float inv = 1.f / s;
#pragma unroll
    for (int j = 0; j < 8; j++) raw[j] = f2bf(e[j] * inv);
    *(int4*)(row + t * 8) = *(const int4*)raw;
}

// ---------------------------------------------------------------------------
// LN1: q = LN(fused + attn) -> qf (fp32) and qb (bf16)
// ---------------------------------------------------------------------------
__global__ __launch_bounds__(256) void ln1_kernel(
    const ushort_t* __restrict__ Fb, const ushort_t* __restrict__ Ab,
    const float* __restrict__ g1, const float* __restrict__ be1,
    float* __restrict__ qf, ushort_t* __restrict__ qb) {
    __shared__ float sm[4];
    const size_t base = (size_t)blockIdx.x * 512;
    const int t = threadIdx.x;
    const float v0 = bf2f(Fb[base + t]) + bf2f(Ab[base + t]);
    const float v1 = bf2f(Fb[base + t + 256]) + bf2f(Ab[base + t + 256]);
    const float mu = blk_reduce_sum(v0 + v1, sm) * (1.f / 512.f);
    const float d0 = v0 - mu, d1 = v1 - mu;
    const float var = blk_reduce_sum(d0 * d0 + d1 * d1, sm) * (1.f / 512.f);
    const float rs = rsqrtf(var + LN_EPS);
    const float y0 = d0 * rs * g1[t] + be1[t];
    const float y1 = d1 * rs * g1[t + 256] + be1[t + 256];
    qf[base + t] = y0;          qf[base + t + 256] = y1;
    qb[base + t] = f2bf(y0);    qb[base + t + 256] = f2bf(y1);
}

// Final LN in place on fp32
__global__ __launch_bounds__(256) void ln2_kernel(
    float* __restrict__ T, const float* __restrict__ g,
    const float* __restrict__ be) {
    __shared__ float sm[4];
    const size_t base = (size_t)blockIdx.x * 512;
    const int t = threadIdx.x;
    const float v0 = T[base + t];
    const float v1 = T[base + t + 256];
    const float mu = blk_reduce_sum(v0 + v1, sm) * (1.f / 512.f);
    const float d0 = v0 - mu, d1 = v1 - mu;
    const float var = blk_reduce_sum(d0 * d0 + d1 * d1, sm) * (1.f / 512.f);
    const float rs = rsqrtf(var + LN_EPS);
    T[base + t] = d0 * rs * g[t] + be[t];
    T[base + t + 256] = d1 * rs * g[t + 256] + be[t + 256];
}

// ---------------------------------------------------------------------------
extern "C" void kernel_launch(void* const* d_in, const int* in_sizes, int n_in,
                              void* d_out, int out_size, void* d_ws, size_t ws_size,
                              hipStream_t stream) {
    const float* NX  = (const float*)d_in[0];
    const float* X   = (const float*)d_in[1];
    const float* CD  = (const float*)d_in[2];
    const float* Wg  = (const float*)d_in[3];
    const float* bg  = (const float*)d_in[4];
    const float* W1  = (const float*)d_in[5];
    const float* b1  = (const float*)d_in[6];
    const float* W2  = (const float*)d_in[7];
    const float* b2  = (const float*)d_in[8];
    const float* g1  = (const float*)d_in[9];
    const float* be1 = (const float*)d_in[10];
    const float* g2  = (const float*)d_in[11];
    const float* be2 = (const float*)d_in[12];

    // ws: 3 slots x 16,777,216 B = 50,331,648 B (proven-safe since R2)
    // slot0: Xb -> attnb (progressive, see header note) -> hbuf
    // slot1: Fb -> W1T/W2T;  slot2: WgT -> XbT -> qb
    // d_out: scores (bf16) -> qf (fp32, final)
    ushort_t* slot0 = (ushort_t*)d_ws;
    ushort_t* slot1 = (ushort_t*)((char*)d_ws + 16777216);
    ushort_t* slot2 = (ushort_t*)((char*)d_ws + 33554432);
    ushort_t* Xb    = slot0;                    // [8][2048][512] bf16
    ushort_t* attnb = slot0;
    ushort_t* hbuf  = slot0;
    ushort_t* Fb    = slot1;
    ushort_t* W1T   = slot1;                    // [1024][512] bf16, 1 MB
    ushort_t* W2T   = slot1 + 524288;           // [512][1024] bf16, 1 MB
    ushort_t* WgT   = slot2;                    // [512][1024] bf16, 1 MB
    ushort_t* XbT   = slot2;                    // [8][512][2048] bf16, 16.78 MB
    ushort_t* qb    = slot2;                    // [BS][512] bf16
    ushort_t* Scb   = (ushort_t*)d_out;         // 4 batches [S][S] bf16
    float*    qf    = (float*)d_out;

    // 1) Wg^T (slot2)
    transpose_cvt<<<dim3(512 / 32, 1024 / 32, 1), 256, 0, stream>>>(
        Wg, WgT, 1024, 512, nullptr);

    // 2) gated fusion -> Fb (128x128 dbuf core; fp32 A converted in staging)
    gate_gemm<<<dim3(4, 128), 256, 0, stream>>>(NX, CD, WgT, bg, Fb);

    // 3) X^T per batch into slot2 (WgT dead) — needed by PV;
    //    fused straight bf16 copy Xb into slot0 — needed by QK
    transpose_cvt<<<dim3(512 / 32, 2048 / 32, 8), 256, 0, stream>>>(
        X, XbT, 2048, 512, Xb);

    // 4) attention in 2 groups of 4 batches; scores in d_out
    for (int g = 0; g < 2; g++) {
        const size_t go = (size_t)g * 4 * S * 512;
        // QK: Sc = (Fb @ Xb^T) * scale (128x128 dbuf; 1024 blocks = 4/CU)
        gemm2_std<0><<<dim3(16, 16, 4), 256, 0, stream>>>(
            Fb + go, D, (long)S * D,
            Xb + go, D, (long)S * D,
            (void*)Scb, S, (long)S * S, D, nullptr, ATTN_SCALE, 0);
        softmax_bf16<<<4 * S, 256, 0, stream>>>(Scb);
        // PV: attn = P @ X  (128x64 dbuf; 512 blocks = 2/CU)
        gemm3_std<0><<<dim3(8, 16, 4), 256, 0, stream>>>(
            Scb, S, (long)S * S,
            XbT + go, S, (long)D * S,
            (void*)(attnb + go), 512, (long)S * 512, S, nullptr, 1.f, 0);
    }

    // 5) q = LN(fused + attn): qf -> d_out (scores dead), qb -> slot2 (XbT dead)
    ln1_kernel<<<BS, 256, 0, stream>>>(Fb, attnb, g1, be1, qf, qb);

    // 6) weight transposes into slot1 (Fb dead after LN1)
    transpose_cvt<<<dim3(1024 / 32, 512 / 32, 1), 256, 0, stream>>>(
        W1, W1T, 512, 1024, nullptr);
    transpose_cvt<<<dim3(512 / 32, 1024 / 32, 1), 256, 0, stream>>>(
        W2, W2T, 1024, 512, nullptr);

    // 7) FFN in 2 halves; hidden half in slot0 (attnb dead); t accumulates in d_out
    for (int h = 0; h < 2; h++) {
        gemm2_std<1><<<dim3(4, 128), 256, 0, stream>>>(
            qb, 512, 0, W1T + (size_t)h * 512 * 512, 512, 0,
            (void*)hbuf, 512, 0, 512, b1 + h * 512, 1.f, 0);
        gemm2_std<2><<<dim3(4, 128), 256, 0, stream>>>(
            hbuf, 512, 0, W2T + h * 512, 1024, 0,
            (void*)qf, 512, 0, 512, b2, 1.f, h == 0 ? 1 : 0);
    }

    // 8) out = LN(t) in place in d_out
    ln2_kernel<<<BS, 256, 0, stream>>>(qf, g2, be2);
}